// Round 8
// baseline (187.532 us; speedup 1.0000x reference)
//
#include <hip/hip_runtime.h>
#include <hip/hip_bf16.h>

// ---------------------------------------------------------------------------
// DynamicFeaturePyramid forward, MI355X.
// attention: B=8, S=4096, D=64 single head; flash-fused bf16 MFMA,
// key-split x4 (no-max softmax -> partials combine by plain weighted sum).
// R8: k_prep deleted (in-register weight cvt); k_out 64-pos tiles (grid 512)
// with x1-gating fused into GEMM3 epilogue; k_final handles x2/3/4 only.
// Workspace (bytes):
//   Q   (b,i,c) bf16  :        0 ..  4194304   } phase 1
//   K   (b,j,c) bf16  :  4194304 ..  8388608   }
//   Vt  (b,c,j) bf16  :  8388608 .. 12582912   }
//   SWb (b,c,i) bf16  :        0 ..  8388608   } phase 2 (aliases Q/K, dead)
//   Op  (p,b,i,c)bf16 : 12582912 .. 29360128   (per-part normalized O)
//   Lp  (p,b,i) fp32  : 29360128 .. 29884416
// ---------------------------------------------------------------------------

typedef __attribute__((ext_vector_type(8))) short s16x8;   // 8 bf16 = 4 VGPRs
typedef __attribute__((ext_vector_type(4))) float f32x4;   // MFMA C/D frag

#define LOG2E 1.44269504088896340736f

__device__ __forceinline__ unsigned int f2bf(float f) {
    unsigned int u = __float_as_uint(f);
    u += 0x7fffu + ((u >> 16) & 1u);   // RNE (inputs finite)
    return u >> 16;
}
__device__ __forceinline__ unsigned int pk2bf(float a, float b) {
    union { __hip_bfloat162 h; unsigned int u; } cv;
    cv.h = __float22bfloat162_rn(make_float2(a, b));   // v_cvt_pk_bf16_f32
    return cv.u;
}
__device__ __forceinline__ float bf2f(unsigned short u) {
    return __uint_as_float((unsigned int)u << 16);
}
__device__ __forceinline__ float fexp2(float x) {      // raw v_exp_f32
    return __builtin_amdgcn_exp2f(x);
}
__device__ __forceinline__ float frcp(float x) {       // raw v_rcp_f32
    return __builtin_amdgcn_rcpf(x);
}
// 8 consecutive fp32 -> bf16x8 fragment (optional scale)
__device__ __forceinline__ s16x8 cvt8(const float* __restrict__ p, float scale) {
    float4 a = ((const float4*)p)[0];
    float4 b = ((const float4*)p)[1];
    union { s16x8 v; uint4 u; } cv;
    cv.u.x = pk2bf(a.x * scale, a.y * scale);
    cv.u.y = pk2bf(a.z * scale, a.w * scale);
    cv.u.z = pk2bf(b.x * scale, b.y * scale);
    cv.u.w = pk2bf(b.z * scale, b.w * scale);
    return cv.v;
}

// ---------------------------------------------------------------------------
// K1: fused (bilinear-upsample + concat) -> gf bf16 tile [pos][c] in LDS ->
// MFMA QKV projection. Weights converted in-register from fp32 (no prep).
// Block: (b, 64 pos = one output row); grid 8*64=512.
// ---------------------------------------------------------------------------
__global__ __launch_bounds__(256) void k_qkv(
    const float* __restrict__ x1, const float* __restrict__ x2,
    const float* __restrict__ x3, const float* __restrict__ x4,
    const float* __restrict__ qw, const float* __restrict__ qb,
    const float* __restrict__ kw, const float* __restrict__ kb,
    const float* __restrict__ vw, const float* __restrict__ vb,
    unsigned short* __restrict__ Qg, unsigned short* __restrict__ Kg,
    unsigned short* __restrict__ Vg) {
  __shared__ __align__(16) unsigned short gfb[64 * 136];    // [pos][c] stride 136
  unsigned int* gfbu = (unsigned int*)gfb;                  // word idx = pos*68 + cp

  const int b = blockIdx.x >> 6;
  const int i0 = (blockIdx.x & 63) << 6;
  const int t = threadIdx.x;

  {
    const int cp = t >> 2, q = t & 3;         // channel pair, row quarter
    const int c0 = cp << 1;
    const int pbase = q << 4;                 // 16 positions each
    const int oy = i0 >> 6;                   // single output row per block
    const int ox0 = pbase;

    if (cp < 16) {                            // x1: direct copy, 2 channels
      const float* s0 = x1 + (((b * 32 + c0) << 12) + (oy << 6) + ox0);
      const float* s1 = s0 + 4096;
      #pragma unroll
      for (int k4 = 0; k4 < 4; k4++) {
        float4 va = ((const float4*)s0)[k4];
        float4 vb = ((const float4*)s1)[k4];
        int p = pbase + k4 * 4;
        gfbu[(p + 0) * 68 + cp] = pk2bf(va.x, vb.x);
        gfbu[(p + 1) * 68 + cp] = pk2bf(va.y, vb.y);
        gfbu[(p + 2) * 68 + cp] = pk2bf(va.z, vb.z);
        gfbu[(p + 3) * 68 + cp] = pk2bf(va.w, vb.w);
      }
    } else {                                  // bilinear upsample, 2 channels
      const float* base; int S, cs;
      if (cp < 32)      { base = x2; S = 32; cs = c0 - 32; }
      else if (cp < 48) { base = x3; S = 16; cs = c0 - 64; }
      else              { base = x4; S = 8;  cs = c0 - 96; }
      const float* pl0 = base + (b * 32 + cs) * S * S;
      const float* pl1 = pl0 + S * S;
      float yf = (float)oy * (float)(S - 1) * (1.0f / 63.0f);
      int y0 = (int)yf; if (y0 > S - 1) y0 = S - 1;
      int y1 = y0 + 1;  if (y1 > S - 1) y1 = S - 1;
      float wy = yf - (float)y0;
      const float* r00 = pl0 + y0 * S; const float* r01 = pl0 + y1 * S;
      const float* r10 = pl1 + y0 * S; const float* r11 = pl1 + y1 * S;
      for (int k = 0; k < 16; k++) {
        int ox = ox0 + k;
        float xf = (float)ox * (float)(S - 1) * (1.0f / 63.0f);
        int xx0 = (int)xf; if (xx0 > S - 1) xx0 = S - 1;
        int xx1 = xx0 + 1; if (xx1 > S - 1) xx1 = S - 1;
        float wx = xf - (float)xx0;
        float a0 = r00[xx0] + wx * (r00[xx1] - r00[xx0]);
        float b0 = r01[xx0] + wx * (r01[xx1] - r01[xx0]);
        float v0 = a0 + wy * (b0 - a0);
        float a1 = r10[xx0] + wx * (r10[xx1] - r10[xx0]);
        float b1 = r11[xx0] + wx * (r11[xx1] - r11[xx0]);
        float v1 = a1 + wy * (b1 - a1);
        gfbu[(pbase + k) * 68 + cp] = pk2bf(v0, v1);
      }
    }
  }
  __syncthreads();

  const int wv = t >> 6, lane = t & 63;
  const int r = lane & 15, qd = lane >> 4;
  const int ocb = wv * 48;

  // A-frags + bias converted in-register from fp32 weights.
  // Each 16-row m-tile lies entirely within one of q/k/v (wave-uniform).
  s16x8 af[3][4];
  float4 bias[3];
  #pragma unroll
  for (int mti = 0; mti < 3; mti++) {
    const int goc = ocb + mti * 16;
    const float* wsrc; const float* bsrc; float scale;
    if (goc < 64)       { wsrc = qw + goc * 128;         bsrc = qb + goc;         scale = LOG2E; }
    else if (goc < 128) { wsrc = kw + (goc - 64) * 128;  bsrc = kb + (goc - 64);  scale = 1.0f; }
    else                { wsrc = vw + (goc - 128) * 128; bsrc = vb + (goc - 128); scale = 1.0f; }
    #pragma unroll
    for (int ks = 0; ks < 4; ks++)
      af[mti][ks] = cvt8(wsrc + r * 128 + ks * 32 + qd * 8, scale);
    float4 bv = *(const float4*)(bsrc + qd * 4);
    bias[mti] = make_float4(bv.x * scale, bv.y * scale, bv.z * scale, bv.w * scale);
  }

  f32x4 zf = {0.f, 0.f, 0.f, 0.f};
  #pragma unroll 1
  for (int nt = 0; nt < 4; nt++) {
    s16x8 bfr[4];
    #pragma unroll
    for (int ks = 0; ks < 4; ks++)
      bfr[ks] = *(const s16x8*)&gfb[(nt * 16 + r) * 136 + ks * 32 + qd * 8];
    f32x4 acc[3] = {zf, zf, zf};
    #pragma unroll
    for (int ks = 0; ks < 4; ks++)
      #pragma unroll
      for (int mti = 0; mti < 3; mti++)
        acc[mti] = __builtin_amdgcn_mfma_f32_16x16x32_bf16(af[mti][ks], bfr[ks], acc[mti], 0, 0, 0);

    const int pos = i0 + nt * 16 + r;
    #pragma unroll
    for (int mti = 0; mti < 3; mti++) {
      const int gmt = wv * 3 + mti;
      float ax = acc[mti].x + bias[mti].x;
      float ay = acc[mti].y + bias[mti].y;
      float az = acc[mti].z + bias[mti].z;
      float aw = acc[mti].w + bias[mti].w;
      if (gmt < 4) {
        uint2 w; w.x = pk2bf(ax, ay); w.y = pk2bf(az, aw);
        *(uint2*)&Qg[(((b << 12) + pos) << 6) + gmt * 16 + qd * 4] = w;
      } else if (gmt < 8) {
        uint2 w; w.x = pk2bf(ax, ay); w.y = pk2bf(az, aw);
        *(uint2*)&Kg[(((b << 12) + pos) << 6) + (gmt - 4) * 16 + qd * 4] = w;
      } else {
        int ocv = (gmt - 8) * 16 + qd * 4;
        Vg[((b * 64 + ocv + 0) << 12) + pos] = (unsigned short)f2bf(ax);
        Vg[((b * 64 + ocv + 1) << 12) + pos] = (unsigned short)f2bf(ay);
        Vg[((b * 64 + ocv + 2) << 12) + pos] = (unsigned short)f2bf(az);
        Vg[((b * 64 + ocv + 3) << 12) + pos] = (unsigned short)f2bf(aw);
      }
    }
  }
}

// ---------------------------------------------------------------------------
// K2: flash attention, transposed (S^T = K*Q^T, O^T = V^T*P^T), key-split x4.
// LDS K/V staging (VGPR prefetch), 32 queries/wave, grid 1024, 4 blocks/CU.
// Raw v_exp_f32; l-sums via MFMA ones-row (accl tile). [R7, unchanged]
// ---------------------------------------------------------------------------
__global__ __launch_bounds__(256, 4) void k_attn(
    const unsigned short* __restrict__ Qg, const unsigned short* __restrict__ Kg,
    const unsigned short* __restrict__ Vg, unsigned short* __restrict__ Op,
    float* __restrict__ Lp) {
  __shared__ __align__(16) unsigned short Kl[64 * 72];
  __shared__ __align__(16) unsigned short Vl[64 * 72];
  __shared__ __align__(16) unsigned short Pl[4][32 * 72];

  const int b = blockIdx.x >> 7;
  const int part = (blockIdx.x >> 5) & 3;
  const int qg = blockIdx.x & 31;
  const int i0 = qg << 7;
  const int t = threadIdx.x;
  const int wv = t >> 6, lane = t & 63;
  const int r = lane & 15, qd = lane >> 4;
  const int qbase = i0 + wv * 32;

  s16x8 qf[2][2];
  #pragma unroll
  for (int nt = 0; nt < 2; nt++)
    #pragma unroll
    for (int ks = 0; ks < 2; ks++)
      qf[nt][ks] = *(const s16x8*)&Qg[(((b << 12) + qbase + nt * 16 + r) << 6) + ks * 32 + qd * 8];

  f32x4 zf = {0.f, 0.f, 0.f, 0.f};
  f32x4 acc[2][4];
  #pragma unroll
  for (int nt = 0; nt < 2; nt++)
    #pragma unroll
    for (int mt = 0; mt < 4; mt++) acc[nt][mt] = zf;
  f32x4 accl[2] = {zf, zf};                  // l-sums: ones-row x P

  const short ob = (r == 0) ? (short)0x3F80 : (short)0;
  const s16x8 vones = {ob, ob, ob, ob, ob, ob, ob, ob};

  const int srow = t >> 3, sseg = t & 7;
  const unsigned short* kt0 = &Kg[(((b << 12) + (part << 10) + srow) << 6) + sseg * 8];
  const unsigned short* vt0 = &Vg[((b * 64 + srow) << 12) + (part << 10) + sseg * 8];
  uint4 pk0 = *(const uint4*)(kt0);
  uint4 pk1 = *(const uint4*)(kt0 + (32 << 6));
  uint4 pv0 = *(const uint4*)(vt0);
  uint4 pv1 = *(const uint4*)(vt0 + (32 << 12));

  for (int it = 0; it < 16; it++) {
    __syncthreads();
    *(uint4*)&Kl[srow * 72 + sseg * 8] = pk0;
    *(uint4*)&Kl[(srow + 32) * 72 + sseg * 8] = pk1;
    *(uint4*)&Vl[srow * 72 + sseg * 8] = pv0;
    *(uint4*)&Vl[(srow + 32) * 72 + sseg * 8] = pv1;
    __syncthreads();
    if (it < 15) {
      int j0 = (it + 1) << 6;
      pk0 = *(const uint4*)(kt0 + (j0 << 6));
      pk1 = *(const uint4*)(kt0 + ((j0 + 32) << 6));
      pv0 = *(const uint4*)(vt0 + j0);
      pv1 = *(const uint4*)(vt0 + (32 << 12) + j0);
    }

    #pragma unroll
    for (int mt = 0; mt < 4; mt++) {
      s16x8 kf0 = *(const s16x8*)&Kl[(mt * 16 + r) * 72 + qd * 8];
      s16x8 kf1 = *(const s16x8*)&Kl[(mt * 16 + r) * 72 + 32 + qd * 8];
      #pragma unroll
      for (int nt = 0; nt < 2; nt++) {
        f32x4 s = __builtin_amdgcn_mfma_f32_16x16x32_bf16(kf0, qf[nt][0], zf, 0, 0, 0);
        s = __builtin_amdgcn_mfma_f32_16x16x32_bf16(kf1, qf[nt][1], s, 0, 0, 0);
        float px = fexp2(fminf(s.x, 80.f));
        float py = fexp2(fminf(s.y, 80.f));
        float pz = fexp2(fminf(s.z, 80.f));
        float pw = fexp2(fminf(s.w, 80.f));
        uint2 w;
        w.x = pk2bf(px, py);
        w.y = pk2bf(pz, pw);
        *(uint2*)&Pl[wv][(nt * 16 + r) * 72 + mt * 16 + qd * 4] = w;
      }
    }
    __builtin_amdgcn_wave_barrier();          // keep P writes before reads

    #pragma unroll
    for (int ks = 0; ks < 2; ks++) {
      s16x8 pf0 = *(const s16x8*)&Pl[wv][(r) * 72 + ks * 32 + qd * 8];
      s16x8 pf1 = *(const s16x8*)&Pl[wv][(16 + r) * 72 + ks * 32 + qd * 8];
      #pragma unroll
      for (int mt = 0; mt < 4; mt++) {
        s16x8 vf = *(const s16x8*)&Vl[(mt * 16 + r) * 72 + ks * 32 + qd * 8];
        acc[0][mt] = __builtin_amdgcn_mfma_f32_16x16x32_bf16(vf, pf0, acc[0][mt], 0, 0, 0);
        acc[1][mt] = __builtin_amdgcn_mfma_f32_16x16x32_bf16(vf, pf1, acc[1][mt], 0, 0, 0);
      }
      accl[0] = __builtin_amdgcn_mfma_f32_16x16x32_bf16(vones, pf0, accl[0], 0, 0, 0);
      accl[1] = __builtin_amdgcn_mfma_f32_16x16x32_bf16(vones, pf1, accl[1], 0, 0, 0);
    }
  }

  #pragma unroll
  for (int nt = 0; nt < 2; nt++) {
    float lv = __shfl(accl[nt].x, r);         // broadcast col sum to all lanes
    float inv = frcp(lv);
    int qrow = qbase + nt * 16 + r;
    unsigned short* orow = &Op[(((part * 8 + b) << 12) + qrow) << 6];
    #pragma unroll
    for (int mt = 0; mt < 4; mt++) {
      uint2 w;
      w.x = pk2bf(acc[nt][mt].x * inv, acc[nt][mt].y * inv);
      w.y = pk2bf(acc[nt][mt].z * inv, acc[nt][mt].w * inv);
      *(uint2*)&orow[mt * 16 + qd * 4] = w;
    }
    if (qd == 0) Lp[((part * 8 + b) << 12) + qrow] = lv;
  }
}

// ---------------------------------------------------------------------------
// K3: combine partials -> Ot[pos][c] -> GEMM1 (ow) -> gf2t[pos][oc] ->
// GEMM2 (g1,relu) -> ht[pos][oc2] -> GEMM3 swapped (g2, sigmoid).
// 64-pos tiles, grid 512 (2 blocks/CU). Wave 0 fuses the x1 gating
// (out1 = x1*(1+sw), oc<32) directly; SWb stored only for oc>=32.
// Weights converted in-register from fp32 (no prep kernel).
// ---------------------------------------------------------------------------
__global__ __launch_bounds__(256) void k_out(
    const unsigned short* __restrict__ Op, const float* __restrict__ Lp,
    const float* __restrict__ ow, const float* __restrict__ obias,
    const float* __restrict__ g1w, const float* __restrict__ g1b,
    const float* __restrict__ g2w, const float* __restrict__ g2b,
    const float* __restrict__ x1, float* __restrict__ out,
    unsigned short* __restrict__ SWb) {
  __shared__ __align__(16) unsigned short Ot[64 * 72];      // [pos][c] c<64
  __shared__ __align__(16) unsigned short gf2t[64 * 136];   // [pos][oc] oc<128
  __shared__ __align__(16) unsigned short ht[64 * 40];      // [pos][oc2] oc2<32
  const int b = blockIdx.x >> 6;
  const int i0 = (blockIdx.x & 63) << 6;
  const int t = threadIdx.x;

  // ---- combine partials: Ot[pos][c] = sum_p (l_p/lsum)*Op[p]; 16 ch/thread
  {
    const int pos = t >> 2, q4 = t & 3;
    const int i = i0 + pos;
    float lp4[4], lsum = 0.f;
    #pragma unroll
    for (int p = 0; p < 4; p++) { lp4[p] = Lp[((p * 8 + b) << 12) + i]; lsum += lp4[p]; }
    float o[16];
    #pragma unroll
    for (int k = 0; k < 16; k++) o[k] = 0.f;
    float invs = frcp(lsum);
    #pragma unroll
    for (int p = 0; p < 4; p++) {
      float w = lp4[p] * invs;
      const uint2* prow = (const uint2*)&Op[((((p * 8 + b) << 12) + i) << 6) + q4 * 16];
      #pragma unroll
      for (int k = 0; k < 4; k++) {
        uint2 u = prow[k];
        o[k * 4 + 0] += w * __uint_as_float(u.x << 16);
        o[k * 4 + 1] += w * __uint_as_float(u.x & 0xFFFF0000u);
        o[k * 4 + 2] += w * __uint_as_float(u.y << 16);
        o[k * 4 + 3] += w * __uint_as_float(u.y & 0xFFFF0000u);
      }
    }
    unsigned int* dst = (unsigned int*)&Ot[pos * 72 + q4 * 16];
    #pragma unroll
    for (int k = 0; k < 8; k++) dst[k] = pk2bf(o[2 * k], o[2 * k + 1]);
  }
  __syncthreads();

  const int wv = t >> 6, lane = t & 63;
  const int r = lane & 15, qd = lane >> 4;
  f32x4 zf = {0.f, 0.f, 0.f, 0.f};

  // ---- GEMM1: gf2[oc=128][pos=64] = ow(128x64) * Ot^T; wave -> 32 oc ----
  {
    const int ocb = wv * 32;
    s16x8 af[2][2];
    #pragma unroll
    for (int mt = 0; mt < 2; mt++)
      #pragma unroll
      for (int ks = 0; ks < 2; ks++)
        af[mt][ks] = cvt8(&ow[(ocb + mt * 16 + r) * 64 + ks * 32 + qd * 8], 1.0f);
    float4 bias[2];
    #pragma unroll
    for (int mt = 0; mt < 2; mt++)
      bias[mt] = *(const float4*)&obias[ocb + mt * 16 + qd * 4];
    #pragma unroll 1
    for (int nt = 0; nt < 4; nt++) {
      s16x8 bfr[2];
      #pragma unroll
      for (int ks = 0; ks < 2; ks++)
        bfr[ks] = *(const s16x8*)&Ot[(nt * 16 + r) * 72 + ks * 32 + qd * 8];
      f32x4 acc[2] = {zf, zf};
      #pragma unroll
      for (int ks = 0; ks < 2; ks++)
        #pragma unroll
        for (int mt = 0; mt < 2; mt++)
          acc[mt] = __builtin_amdgcn_mfma_f32_16x16x32_bf16(af[mt][ks], bfr[ks], acc[mt], 0, 0, 0);
      #pragma unroll
      for (int mt = 0; mt < 2; mt++) {
        uint2 w;
        w.x = pk2bf(acc[mt].x + bias[mt].x, acc[mt].y + bias[mt].y);
        w.y = pk2bf(acc[mt].z + bias[mt].z, acc[mt].w + bias[mt].w);
        *(uint2*)&gf2t[(nt * 16 + r) * 136 + ocb + mt * 16 + qd * 4] = w;
      }
    }
  }
  __syncthreads();

  // ---- GEMM2: h[oc2=32][pos=64] = g1(32x128) * gf2t^T; wave -> 16 pos ----
  {
    s16x8 af[2][4];
    #pragma unroll
    for (int mt = 0; mt < 2; mt++)
      #pragma unroll
      for (int ks = 0; ks < 4; ks++)
        af[mt][ks] = cvt8(&g1w[(mt * 16 + r) * 128 + ks * 32 + qd * 8], 1.0f);
    float4 bias[2];
    #pragma unroll
    for (int mt = 0; mt < 2; mt++)
      bias[mt] = *(const float4*)&g1b[mt * 16 + qd * 4];
    const int pn = wv * 16 + r;
    s16x8 bfr[4];
    #pragma unroll
    for (int ks = 0; ks < 4; ks++)
      bfr[ks] = *(const s16x8*)&gf2t[pn * 136 + ks * 32 + qd * 8];
    f32x4 acc[2] = {zf, zf};
    #pragma unroll
    for (int ks = 0; ks < 4; ks++)
      #pragma unroll
      for (int mt = 0; mt < 2; mt++)
        acc[mt] = __builtin_amdgcn_mfma_f32_16x16x32_bf16(af[mt][ks], bfr[ks], acc[mt], 0, 0, 0);
    #pragma unroll
    for (int mt = 0; mt < 2; mt++) {
      uint2 w;
      w.x = pk2bf(fmaxf(acc[mt].x + bias[mt].x, 0.f), fmaxf(acc[mt].y + bias[mt].y, 0.f));
      w.y = pk2bf(fmaxf(acc[mt].z + bias[mt].z, 0.f), fmaxf(acc[mt].w + bias[mt].w, 0.f));
      *(uint2*)&ht[pn * 40 + mt * 16 + qd * 4] = w;
    }
  }
  __syncthreads();

  // ---- GEMM3 (swapped): sw[pos][oc3] = ht(pos x 32) * g2^T; K=32 ----
  // wave 0 (oc3<32): fused x1 gating -> out1 float4; others -> SWb bf16.
  {
    const int nb = wv * 32;
    s16x8 bfg[2];
    float bias[2];
    #pragma unroll
    for (int ntl = 0; ntl < 2; ntl++) {
      bfg[ntl] = cvt8(&g2w[(nb + ntl * 16 + r) * 32 + qd * 8], 1.0f);
      bias[ntl] = g2b[nb + ntl * 16 + r];
    }
    #pragma unroll 1
    for (int mt = 0; mt < 4; mt++) {
      s16x8 af = *(const s16x8*)&ht[(mt * 16 + r) * 40 + qd * 8];
      #pragma unroll
      for (int ntl = 0; ntl < 2; ntl++) {
        f32x4 acc = __builtin_amdgcn_mfma_f32_16x16x32_bf16(af, bfg[ntl], zf, 0, 0, 0);
        const int oc3 = nb + ntl * 16 + r;
        float s0 = frcp(1.0f + fexp2(-LOG2E * (acc.x + bias[ntl])));
        float s1 = frcp(1.0f + fexp2(-LOG2E * (acc.y + bias[ntl])));
        float s2 = frcp(1.0f + fexp2(-LOG2E * (acc.z + bias[ntl])));
        float s3 = frcp(1.0f + fexp2(-LOG2E * (acc.w + bias[ntl])));
        if (nb == 0) {                        // x1 gating fused (oc3 < 32)
          const int off = ((b * 32 + oc3) << 12) + i0 + mt * 16 + qd * 4;
          float4 xv = *(const float4*)&x1[off];
          float4 o4;
          o4.x = xv.x * (1.f + s0); o4.y = xv.y * (1.f + s1);
          o4.z = xv.z * (1.f + s2); o4.w = xv.w * (1.f + s3);
          *(float4*)&out[off] = o4;
        } else {
          uint2 w; w.x = pk2bf(s0, s1); w.y = pk2bf(s2, s3);
          *(uint2*)&SWb[((b * 128 + oc3) << 12) + i0 + mt * 16 + qd * 4] = w;
        }
      }
    }
  }
}

// ---------------------------------------------------------------------------
// K4: gated outputs x2/x3/x4 only: x_k*(1+downsample(w_k)). SW is bf16.
// ---------------------------------------------------------------------------
__device__ __forceinline__ float bilin64(const unsigned short* __restrict__ p,
                                         int oy, int ox, int n) {
  float yf = (float)oy * 63.0f / (float)n;
  int y0 = (int)yf; if (y0 > 63) y0 = 63;
  int y1 = y0 + 1;  if (y1 > 63) y1 = 63;
  float wy = yf - (float)y0;
  float xf = (float)ox * 63.0f / (float)n;
  int x0 = (int)xf; if (x0 > 63) x0 = 63;
  int x1 = x0 + 1;  if (x1 > 63) x1 = 63;
  float wx = xf - (float)x0;
  float v00 = bf2f(p[y0 * 64 + x0]), v01 = bf2f(p[y0 * 64 + x1]);
  float v10 = bf2f(p[y1 * 64 + x0]), v11 = bf2f(p[y1 * 64 + x1]);
  float top = v00 + wx * (v01 - v00);
  float bot = v10 + wx * (v11 - v10);
  return top + wy * (bot - top);
}

__global__ __launch_bounds__(256) void k_final(
    const float* __restrict__ x2, const float* __restrict__ x3,
    const float* __restrict__ x4,
    const unsigned short* __restrict__ SWb, float* __restrict__ out) {
  const int N1 = 1048576, N2 = 262144, N3 = 65536, N4 = 16384;
  int idx = blockIdx.x * 256 + threadIdx.x;
  if (idx < N2) {
    int b = idx >> 15, rr = idx & 32767;
    int c = rr >> 10, oy = (rr >> 5) & 31, ox = rr & 31;
    float w = bilin64(SWb + ((b * 128 + 32 + c) << 12), oy, ox, 31);
    out[N1 + idx] = x2[idx] * (1.f + w);
  } else if (idx < N2 + N3) {
    int i3 = idx - N2;
    int b = i3 >> 13, rr = i3 & 8191;
    int c = rr >> 8, oy = (rr >> 4) & 15, ox = rr & 15;
    float w = bilin64(SWb + ((b * 128 + 64 + c) << 12), oy, ox, 15);
    out[N1 + idx] = x3[i3] * (1.f + w);
  } else if (idx < N2 + N3 + N4) {
    int i4 = idx - N2 - N3;
    int b = i4 >> 11, rr = i4 & 2047;
    int c = rr >> 6, oy = (rr >> 3) & 7, ox = rr & 7;
    float w = bilin64(SWb + ((b * 128 + 96 + c) << 12), oy, ox, 7);
    out[N1 + idx] = x4[i4] * (1.f + w);
  }
}

// ---------------------------------------------------------------------------
extern "C" void kernel_launch(void* const* d_in, const int* in_sizes, int n_in,
                              void* d_out, int out_size, void* d_ws, size_t ws_size,
                              hipStream_t stream) {
  const float* x1  = (const float*)d_in[0];
  const float* x2  = (const float*)d_in[1];
  const float* x3  = (const float*)d_in[2];
  const float* x4  = (const float*)d_in[3];
  const float* qw  = (const float*)d_in[4];
  const float* qb  = (const float*)d_in[5];
  const float* kw  = (const float*)d_in[6];
  const float* kb  = (const float*)d_in[7];
  const float* vw  = (const float*)d_in[8];
  const float* vb  = (const float*)d_in[9];
  const float* ow  = (const float*)d_in[10];
  const float* ob  = (const float*)d_in[11];
  const float* g1w = (const float*)d_in[12];
  const float* g1b = (const float*)d_in[13];
  const float* g2w = (const float*)d_in[14];
  const float* g2b = (const float*)d_in[15];
  float* out = (float*)d_out;

  char* ws = (char*)d_ws;
  unsigned short* Qg  = (unsigned short*)(ws + 0);
  unsigned short* Kg  = (unsigned short*)(ws + 4194304);
  unsigned short* Vg  = (unsigned short*)(ws + 8388608);
  unsigned short* SWb = (unsigned short*)(ws + 0);          // aliases Q/K (dead)
  unsigned short* Op  = (unsigned short*)(ws + 12582912);
  float* Lp   = (float*)(ws + 29360128);

  k_qkv<<<512, 256, 0, stream>>>(x1, x2, x3, x4, qw, qb, kw, kb, vw, vb,
                                 Qg, Kg, Vg);
  k_attn<<<1024, 256, 0, stream>>>(Qg, Kg, Vg, Op, Lp);
  k_out<<<512, 256, 0, stream>>>(Op, Lp, ow, ob, g1w, g1b, g2w, g2b,
                                 x1, out, SWb);
  k_final<<<1344, 256, 0, stream>>>(x2, x3, x4, SWb, out);
}

// Round 10
// 178.997 us; speedup vs baseline: 1.0477x; 1.0477x over previous
//
#include <hip/hip_runtime.h>
#include <hip/hip_bf16.h>

// ---------------------------------------------------------------------------
// DynamicFeaturePyramid forward, MI355X.
// R10: four regular kernels; k_qkv and k_out re-tiled to 32-position blocks
// (grid 1024 = 4 blocks/CU) for occupancy; k_attn = R7 proven structure
// (minus dead fmin clamp); k_final = x2/3/4 only (x1 gate fused in k_out).
// Workspace: Q 0..4M, K 4M..8M, Vt 8M..12M, SWb aliases 0..8M (phase 3+),
// Op 12.6M..29.4M, Lp 29.4M..29.9M.
// ---------------------------------------------------------------------------

typedef __attribute__((ext_vector_type(8))) short s16x8;   // 8 bf16 = 4 VGPRs
typedef __attribute__((ext_vector_type(4))) float f32x4;   // MFMA C/D frag

#define LOG2E 1.44269504088896340736f

__device__ __forceinline__ unsigned int f2bf(float f) {
    unsigned int u = __float_as_uint(f);
    u += 0x7fffu + ((u >> 16) & 1u);   // RNE (inputs finite)
    return u >> 16;
}
__device__ __forceinline__ unsigned int pk2bf(float a, float b) {
    union { __hip_bfloat162 h; unsigned int u; } cv;
    cv.h = __float22bfloat162_rn(make_float2(a, b));   // v_cvt_pk_bf16_f32
    return cv.u;
}
__device__ __forceinline__ float bf2f(unsigned short u) {
    return __uint_as_float((unsigned int)u << 16);
}
__device__ __forceinline__ float fexp2(float x) { return __builtin_amdgcn_exp2f(x); }
__device__ __forceinline__ float frcp(float x)  { return __builtin_amdgcn_rcpf(x); }
__device__ __forceinline__ s16x8 cvt8(const float* __restrict__ p, float scale) {
    float4 a = ((const float4*)p)[0];
    float4 b = ((const float4*)p)[1];
    union { s16x8 v; uint4 u; } cv;
    cv.u.x = pk2bf(a.x * scale, a.y * scale);
    cv.u.y = pk2bf(a.z * scale, a.w * scale);
    cv.u.z = pk2bf(b.x * scale, b.y * scale);
    cv.u.w = pk2bf(b.z * scale, b.w * scale);
    return cv.v;
}

// ---------------------------------------------------------------------------
// K1: upsample+concat -> gf bf16 [pos][c] (32-pos tile) -> MFMA QKV proj.
// Grid 1024: b = blk>>7, tile = blk&127. 4 blocks/CU.
// ---------------------------------------------------------------------------
__global__ __launch_bounds__(256, 4) void k_qkv(
    const float* __restrict__ x1, const float* __restrict__ x2,
    const float* __restrict__ x3, const float* __restrict__ x4,
    const float* __restrict__ qw, const float* __restrict__ qb,
    const float* __restrict__ kw, const float* __restrict__ kb,
    const float* __restrict__ vw, const float* __restrict__ vb,
    unsigned short* __restrict__ Qg, unsigned short* __restrict__ Kg,
    unsigned short* __restrict__ Vg) {
  __shared__ __align__(16) unsigned short gfb[32 * 136];    // [pos][c]
  unsigned int* gfbu = (unsigned int*)gfb;                  // pos*68 + cp

  const int blk = blockIdx.x;
  const int b = blk >> 7;
  const int i0 = (blk & 127) << 5;
  const int t = threadIdx.x;
  const int wv = t >> 6, lane = t & 63;
  const int r = lane & 15, qd = lane >> 4;
  f32x4 zf = {0.f, 0.f, 0.f, 0.f};

  {
    const int cp = t >> 2, q = t & 3;
    const int c0 = cp << 1;
    const int pbase = q << 3;                   // 8 positions each
    const int oy = i0 >> 6;
    const int ox0 = (i0 & 63) | (q << 3);

    if (cp < 16) {                              // x1 direct, 2 channels
      const float* s0 = x1 + (((b * 32 + c0) << 12) + (oy << 6) + ox0);
      const float* s1 = s0 + 4096;
      #pragma unroll
      for (int k4 = 0; k4 < 2; k4++) {
        float4 va = ((const float4*)s0)[k4];
        float4 vb = ((const float4*)s1)[k4];
        int p = pbase + k4 * 4;
        gfbu[(p + 0) * 68 + cp] = pk2bf(va.x, vb.x);
        gfbu[(p + 1) * 68 + cp] = pk2bf(va.y, vb.y);
        gfbu[(p + 2) * 68 + cp] = pk2bf(va.z, vb.z);
        gfbu[(p + 3) * 68 + cp] = pk2bf(va.w, vb.w);
      }
    } else {                                    // bilinear upsample, 2 ch
      const float* base; int S, cs;
      if (cp < 32)      { base = x2; S = 32; cs = c0 - 32; }
      else if (cp < 48) { base = x3; S = 16; cs = c0 - 64; }
      else              { base = x4; S = 8;  cs = c0 - 96; }
      const float* pl0 = base + (b * 32 + cs) * S * S;
      const float* pl1 = pl0 + S * S;
      float yf = (float)oy * (float)(S - 1) * (1.0f / 63.0f);
      int y0 = (int)yf; if (y0 > S - 1) y0 = S - 1;
      int y1 = y0 + 1;  if (y1 > S - 1) y1 = S - 1;
      float wy = yf - (float)y0;
      const float* r00 = pl0 + y0 * S; const float* r01 = pl0 + y1 * S;
      const float* r10 = pl1 + y0 * S; const float* r11 = pl1 + y1 * S;
      for (int k = 0; k < 8; k++) {
        int ox = ox0 + k;
        float xf = (float)ox * (float)(S - 1) * (1.0f / 63.0f);
        int xx0 = (int)xf; if (xx0 > S - 1) xx0 = S - 1;
        int xx1 = xx0 + 1; if (xx1 > S - 1) xx1 = S - 1;
        float wx = xf - (float)xx0;
        float a0 = r00[xx0] + wx * (r00[xx1] - r00[xx0]);
        float b0 = r01[xx0] + wx * (r01[xx1] - r01[xx0]);
        float v0 = a0 + wy * (b0 - a0);
        float a1 = r10[xx0] + wx * (r10[xx1] - r10[xx0]);
        float b1 = r11[xx0] + wx * (r11[xx1] - r11[xx0]);
        float v1 = a1 + wy * (b1 - a1);
        gfbu[(pbase + k) * 68 + cp] = pk2bf(v0, v1);
      }
    }
  }
  __syncthreads();

  const int ocb = wv * 48;
  s16x8 af[3][4];
  float4 bias[3];
  #pragma unroll
  for (int mti = 0; mti < 3; mti++) {
    const int goc = ocb + mti * 16;
    const float* wsrc; const float* bsrc; float scale;
    if (goc < 64)       { wsrc = qw + goc * 128;         bsrc = qb + goc;         scale = LOG2E; }
    else if (goc < 128) { wsrc = kw + (goc - 64) * 128;  bsrc = kb + (goc - 64);  scale = 1.0f; }
    else                { wsrc = vw + (goc - 128) * 128; bsrc = vb + (goc - 128); scale = 1.0f; }
    #pragma unroll
    for (int ks = 0; ks < 4; ks++)
      af[mti][ks] = cvt8(wsrc + r * 128 + ks * 32 + qd * 8, scale);
    float4 bv = *(const float4*)(bsrc + qd * 4);
    bias[mti] = make_float4(bv.x * scale, bv.y * scale, bv.z * scale, bv.w * scale);
  }

  #pragma unroll
  for (int nt = 0; nt < 2; nt++) {
    s16x8 bfr[4];
    #pragma unroll
    for (int ks = 0; ks < 4; ks++)
      bfr[ks] = *(const s16x8*)&gfb[(nt * 16 + r) * 136 + ks * 32 + qd * 8];
    f32x4 acc[3] = {zf, zf, zf};
    #pragma unroll
    for (int ks = 0; ks < 4; ks++)
      #pragma unroll
      for (int mti = 0; mti < 3; mti++)
        acc[mti] = __builtin_amdgcn_mfma_f32_16x16x32_bf16(af[mti][ks], bfr[ks], acc[mti], 0, 0, 0);

    const int pos = i0 + nt * 16 + r;
    #pragma unroll
    for (int mti = 0; mti < 3; mti++) {
      const int gmt = wv * 3 + mti;
      float ax = acc[mti].x + bias[mti].x;
      float ay = acc[mti].y + bias[mti].y;
      float az = acc[mti].z + bias[mti].z;
      float aw = acc[mti].w + bias[mti].w;
      if (gmt < 4) {
        uint2 w; w.x = pk2bf(ax, ay); w.y = pk2bf(az, aw);
        *(uint2*)&Qg[(((b << 12) + pos) << 6) + gmt * 16 + qd * 4] = w;
      } else if (gmt < 8) {
        uint2 w; w.x = pk2bf(ax, ay); w.y = pk2bf(az, aw);
        *(uint2*)&Kg[(((b << 12) + pos) << 6) + (gmt - 4) * 16 + qd * 4] = w;
      } else {
        int ocv = (gmt - 8) * 16 + qd * 4;
        Vg[((b * 64 + ocv + 0) << 12) + pos] = (unsigned short)f2bf(ax);
        Vg[((b * 64 + ocv + 1) << 12) + pos] = (unsigned short)f2bf(ay);
        Vg[((b * 64 + ocv + 2) << 12) + pos] = (unsigned short)f2bf(az);
        Vg[((b * 64 + ocv + 3) << 12) + pos] = (unsigned short)f2bf(aw);
      }
    }
  }
}

// ---------------------------------------------------------------------------
// K2: flash attention, transposed (S^T = K*Q^T, O^T = V^T*P^T), key-split x4.
// LDS K/V staging (VGPR prefetch), 32 queries/wave, grid 1024, 4 blocks/CU.
// Raw v_exp_f32; l-sums via MFMA ones-row. [R7 proven; clamp removed]
// ---------------------------------------------------------------------------
__global__ __launch_bounds__(256, 4) void k_attn(
    const unsigned short* __restrict__ Qg, const unsigned short* __restrict__ Kg,
    const unsigned short* __restrict__ Vg, unsigned short* __restrict__ Op,
    float* __restrict__ Lp) {
  __shared__ __align__(16) unsigned short Kl[64 * 72];
  __shared__ __align__(16) unsigned short Vl[64 * 72];
  __shared__ __align__(16) unsigned short Pl[4][32 * 72];

  const int b = blockIdx.x >> 7;
  const int part = (blockIdx.x >> 5) & 3;
  const int qg = blockIdx.x & 31;
  const int i0 = qg << 7;
  const int t = threadIdx.x;
  const int wv = t >> 6, lane = t & 63;
  const int r = lane & 15, qd = lane >> 4;
  const int qbase = i0 + wv * 32;

  s16x8 qf[2][2];
  #pragma unroll
  for (int nt = 0; nt < 2; nt++)
    #pragma unroll
    for (int ks = 0; ks < 2; ks++)
      qf[nt][ks] = *(const s16x8*)&Qg[(((b << 12) + qbase + nt * 16 + r) << 6) + ks * 32 + qd * 8];

  f32x4 zf = {0.f, 0.f, 0.f, 0.f};
  f32x4 acc[2][4];
  #pragma unroll
  for (int nt = 0; nt < 2; nt++)
    #pragma unroll
    for (int mt = 0; mt < 4; mt++) acc[nt][mt] = zf;
  f32x4 accl[2] = {zf, zf};                  // l-sums: ones-row x P

  const short ob = (r == 0) ? (short)0x3F80 : (short)0;
  const s16x8 vones = {ob, ob, ob, ob, ob, ob, ob, ob};

  const int srow = t >> 3, sseg = t & 7;
  const unsigned short* kt0 = &Kg[(((b << 12) + (part << 10) + srow) << 6) + sseg * 8];
  const unsigned short* vt0 = &Vg[((b * 64 + srow) << 12) + (part << 10) + sseg * 8];
  uint4 pk0 = *(const uint4*)(kt0);
  uint4 pk1 = *(const uint4*)(kt0 + (32 << 6));
  uint4 pv0 = *(const uint4*)(vt0);
  uint4 pv1 = *(const uint4*)(vt0 + (32 << 12));

  for (int it = 0; it < 16; it++) {
    __syncthreads();
    *(uint4*)&Kl[srow * 72 + sseg * 8] = pk0;
    *(uint4*)&Kl[(srow + 32) * 72 + sseg * 8] = pk1;
    *(uint4*)&Vl[srow * 72 + sseg * 8] = pv0;
    *(uint4*)&Vl[(srow + 32) * 72 + sseg * 8] = pv1;
    __syncthreads();
    if (it < 15) {
      int j0 = (it + 1) << 6;
      pk0 = *(const uint4*)(kt0 + (j0 << 6));
      pk1 = *(const uint4*)(kt0 + ((j0 + 32) << 6));
      pv0 = *(const uint4*)(vt0 + j0);
      pv1 = *(const uint4*)(vt0 + (32 << 12) + j0);
    }

    #pragma unroll
    for (int mt = 0; mt < 4; mt++) {
      s16x8 kf0 = *(const s16x8*)&Kl[(mt * 16 + r) * 72 + qd * 8];
      s16x8 kf1 = *(const s16x8*)&Kl[(mt * 16 + r) * 72 + 32 + qd * 8];
      #pragma unroll
      for (int nt = 0; nt < 2; nt++) {
        f32x4 s = __builtin_amdgcn_mfma_f32_16x16x32_bf16(kf0, qf[nt][0], zf, 0, 0, 0);
        s = __builtin_amdgcn_mfma_f32_16x16x32_bf16(kf1, qf[nt][1], s, 0, 0, 0);
        float px = fexp2(s.x);
        float py = fexp2(s.y);
        float pz = fexp2(s.z);
        float pw = fexp2(s.w);
        uint2 w;
        w.x = pk2bf(px, py);
        w.y = pk2bf(pz, pw);
        *(uint2*)&Pl[wv][(nt * 16 + r) * 72 + mt * 16 + qd * 4] = w;
      }
    }
    __builtin_amdgcn_wave_barrier();          // keep P writes before reads

    #pragma unroll
    for (int ks = 0; ks < 2; ks++) {
      s16x8 pf0 = *(const s16x8*)&Pl[wv][(r) * 72 + ks * 32 + qd * 8];
      s16x8 pf1 = *(const s16x8*)&Pl[wv][(16 + r) * 72 + ks * 32 + qd * 8];
      #pragma unroll
      for (int mt = 0; mt < 4; mt++) {
        s16x8 vf = *(const s16x8*)&Vl[(mt * 16 + r) * 72 + ks * 32 + qd * 8];
        acc[0][mt] = __builtin_amdgcn_mfma_f32_16x16x32_bf16(vf, pf0, acc[0][mt], 0, 0, 0);
        acc[1][mt] = __builtin_amdgcn_mfma_f32_16x16x32_bf16(vf, pf1, acc[1][mt], 0, 0, 0);
      }
      accl[0] = __builtin_amdgcn_mfma_f32_16x16x32_bf16(vones, pf0, accl[0], 0, 0, 0);
      accl[1] = __builtin_amdgcn_mfma_f32_16x16x32_bf16(vones, pf1, accl[1], 0, 0, 0);
    }
  }

  #pragma unroll
  for (int nt = 0; nt < 2; nt++) {
    float lv = __shfl(accl[nt].x, r);         // broadcast col sum to all lanes
    float inv = frcp(lv);
    int qrow = qbase + nt * 16 + r;
    unsigned short* orow = &Op[(((part * 8 + b) << 12) + qrow) << 6];
    #pragma unroll
    for (int mt = 0; mt < 4; mt++) {
      uint2 w;
      w.x = pk2bf(acc[nt][mt].x * inv, acc[nt][mt].y * inv);
      w.y = pk2bf(acc[nt][mt].z * inv, acc[nt][mt].w * inv);
      *(uint2*)&orow[mt * 16 + qd * 4] = w;
    }
    if (qd == 0) Lp[((part * 8 + b) << 12) + qrow] = lv;
  }
}

// ---------------------------------------------------------------------------
// K3: combine partials -> Ot -> GEMM1(ow) -> GEMM2(g1,relu) -> GEMM3(g2,
// sigmoid) with fused x1 gating (wave 0). 32-pos tiles, grid 1024.
// ---------------------------------------------------------------------------
__global__ __launch_bounds__(256, 4) void k_out(
    const unsigned short* __restrict__ Op, const float* __restrict__ Lp,
    const float* __restrict__ ow, const float* __restrict__ obias,
    const float* __restrict__ g1w, const float* __restrict__ g1b,
    const float* __restrict__ g2w, const float* __restrict__ g2b,
    const float* __restrict__ x1, float* __restrict__ out,
    unsigned short* __restrict__ SWb) {
  __shared__ __align__(16) unsigned short Ot[32 * 72];
  __shared__ __align__(16) unsigned short gf2t[32 * 136];
  __shared__ __align__(16) unsigned short ht[32 * 40];
  const int blk = blockIdx.x;
  const int b = blk >> 7;
  const int i0 = (blk & 127) << 5;
  const int t = threadIdx.x;
  const int wv = t >> 6, lane = t & 63;
  const int r = lane & 15, qd = lane >> 4;
  f32x4 zf = {0.f, 0.f, 0.f, 0.f};

  // combine partials: Ot[pos][c] = sum_p (l_p/lsum)*Op[p]; 8 ch/thread
  {
    const int pos = t >> 3, seg = t & 7;
    const int i = i0 + pos;
    float lp4[4], lsum = 0.f;
    #pragma unroll
    for (int p = 0; p < 4; p++) { lp4[p] = Lp[((p * 8 + b) << 12) + i]; lsum += lp4[p]; }
    float o[8];
    #pragma unroll
    for (int k = 0; k < 8; k++) o[k] = 0.f;
    float invs = frcp(lsum);
    #pragma unroll
    for (int p = 0; p < 4; p++) {
      float w = lp4[p] * invs;
      uint4 u = *(const uint4*)&Op[((((p * 8 + b) << 12) + i) << 6) + seg * 8];
      o[0] += w * __uint_as_float(u.x << 16);
      o[1] += w * __uint_as_float(u.x & 0xFFFF0000u);
      o[2] += w * __uint_as_float(u.y << 16);
      o[3] += w * __uint_as_float(u.y & 0xFFFF0000u);
      o[4] += w * __uint_as_float(u.z << 16);
      o[5] += w * __uint_as_float(u.z & 0xFFFF0000u);
      o[6] += w * __uint_as_float(u.w << 16);
      o[7] += w * __uint_as_float(u.w & 0xFFFF0000u);
    }
    unsigned int* dst = (unsigned int*)&Ot[pos * 72 + seg * 8];
    #pragma unroll
    for (int k = 0; k < 4; k++) dst[k] = pk2bf(o[2 * k], o[2 * k + 1]);
  }
  __syncthreads();

  // GEMM1: gf2[oc=128][pos=32] = ow(128x64) * Ot^T; wave -> 32 oc
  {
    const int ocb = wv * 32;
    s16x8 af[2][2];
    #pragma unroll
    for (int mt = 0; mt < 2; mt++)
      #pragma unroll
      for (int ks = 0; ks < 2; ks++)
        af[mt][ks] = cvt8(&ow[(ocb + mt * 16 + r) * 64 + ks * 32 + qd * 8], 1.0f);
    float4 bias[2];
    #pragma unroll
    for (int mt = 0; mt < 2; mt++)
      bias[mt] = *(const float4*)&obias[ocb + mt * 16 + qd * 4];
    #pragma unroll
    for (int nt = 0; nt < 2; nt++) {
      s16x8 bfr[2];
      #pragma unroll
      for (int ks = 0; ks < 2; ks++)
        bfr[ks] = *(const s16x8*)&Ot[(nt * 16 + r) * 72 + ks * 32 + qd * 8];
      f32x4 acc[2] = {zf, zf};
      #pragma unroll
      for (int ks = 0; ks < 2; ks++)
        #pragma unroll
        for (int mt = 0; mt < 2; mt++)
          acc[mt] = __builtin_amdgcn_mfma_f32_16x16x32_bf16(af[mt][ks], bfr[ks], acc[mt], 0, 0, 0);
      #pragma unroll
      for (int mt = 0; mt < 2; mt++) {
        uint2 w;
        w.x = pk2bf(acc[mt].x + bias[mt].x, acc[mt].y + bias[mt].y);
        w.y = pk2bf(acc[mt].z + bias[mt].z, acc[mt].w + bias[mt].w);
        *(uint2*)&gf2t[(nt * 16 + r) * 136 + ocb + mt * 16 + qd * 4] = w;
      }
    }
  }
  __syncthreads();

  // GEMM2: h[oc2=32][pos=32] = g1(32x128)*gf2t^T; wave -> (mt, pos-tile)
  {
    const int mt = wv & 1, pt = wv >> 1;
    s16x8 af[4];
    #pragma unroll
    for (int ks = 0; ks < 4; ks++)
      af[ks] = cvt8(&g1w[(mt * 16 + r) * 128 + ks * 32 + qd * 8], 1.0f);
    float4 bias = *(const float4*)&g1b[mt * 16 + qd * 4];
    s16x8 bfr[4];
    #pragma unroll
    for (int ks = 0; ks < 4; ks++)
      bfr[ks] = *(const s16x8*)&gf2t[(pt * 16 + r) * 136 + ks * 32 + qd * 8];
    f32x4 acc = zf;
    #pragma unroll
    for (int ks = 0; ks < 4; ks++)
      acc = __builtin_amdgcn_mfma_f32_16x16x32_bf16(af[ks], bfr[ks], acc, 0, 0, 0);
    uint2 w;
    w.x = pk2bf(fmaxf(acc.x + bias.x, 0.f), fmaxf(acc.y + bias.y, 0.f));
    w.y = pk2bf(fmaxf(acc.z + bias.z, 0.f), fmaxf(acc.w + bias.w, 0.f));
    *(uint2*)&ht[(pt * 16 + r) * 40 + mt * 16 + qd * 4] = w;
  }
  __syncthreads();

  // GEMM3 (swapped): sw[pos][oc3] = ht * g2^T; K=32; wave0 fuses x1 gate
  {
    const int nb = wv * 32;
    s16x8 bfg[2];
    float bias[2];
    #pragma unroll
    for (int ntl = 0; ntl < 2; ntl++) {
      bfg[ntl] = cvt8(&g2w[(nb + ntl * 16 + r) * 32 + qd * 8], 1.0f);
      bias[ntl] = g2b[nb + ntl * 16 + r];
    }
    #pragma unroll
    for (int mt = 0; mt < 2; mt++) {
      s16x8 af = *(const s16x8*)&ht[(mt * 16 + r) * 40 + qd * 8];
      #pragma unroll
      for (int ntl = 0; ntl < 2; ntl++) {
        f32x4 acc = __builtin_amdgcn_mfma_f32_16x16x32_bf16(af, bfg[ntl], zf, 0, 0, 0);
        const int oc3 = nb + ntl * 16 + r;
        float s0 = frcp(1.0f + fexp2(-LOG2E * (acc.x + bias[ntl])));
        float s1 = frcp(1.0f + fexp2(-LOG2E * (acc.y + bias[ntl])));
        float s2 = frcp(1.0f + fexp2(-LOG2E * (acc.z + bias[ntl])));
        float s3 = frcp(1.0f + fexp2(-LOG2E * (acc.w + bias[ntl])));
        if (nb == 0) {                        // x1 gating fused (oc3 < 32)
          const int off = ((b * 32 + oc3) << 12) + i0 + mt * 16 + qd * 4;
          float4 xv = *(const float4*)&x1[off];
          float4 o4;
          o4.x = xv.x * (1.f + s0); o4.y = xv.y * (1.f + s1);
          o4.z = xv.z * (1.f + s2); o4.w = xv.w * (1.f + s3);
          *(float4*)&out[off] = o4;
        } else {
          uint2 w; w.x = pk2bf(s0, s1); w.y = pk2bf(s2, s3);
          *(uint2*)&SWb[((b * 128 + oc3) << 12) + i0 + mt * 16 + qd * 4] = w;
        }
      }
    }
  }
}

// ---------------------------------------------------------------------------
// K4: gated outputs x2/x3/x4 only: x_k*(1+downsample(w_k)). SW is bf16.
// ---------------------------------------------------------------------------
__device__ __forceinline__ float bilin64(const unsigned short* __restrict__ p,
                                         int oy, int ox, int n) {
  float yf = (float)oy * 63.0f / (float)n;
  int y0 = (int)yf; if (y0 > 63) y0 = 63;
  int y1 = y0 + 1;  if (y1 > 63) y1 = 63;
  float wy = yf - (float)y0;
  float xf = (float)ox * 63.0f / (float)n;
  int x0 = (int)xf; if (x0 > 63) x0 = 63;
  int x1 = x0 + 1;  if (x1 > 63) x1 = 63;
  float wx = xf - (float)x0;
  float v00 = bf2f(p[y0 * 64 + x0]), v01 = bf2f(p[y0 * 64 + x1]);
  float v10 = bf2f(p[y1 * 64 + x0]), v11 = bf2f(p[y1 * 64 + x1]);
  float top = v00 + wx * (v01 - v00);
  float bot = v10 + wx * (v11 - v10);
  return top + wy * (bot - top);
}

__global__ __launch_bounds__(256) void k_final(
    const float* __restrict__ x2, const float* __restrict__ x3,
    const float* __restrict__ x4,
    const unsigned short* __restrict__ SWb, float* __restrict__ out) {
  const int N1 = 1048576, N2 = 262144, N3 = 65536, N4 = 16384;
  int idx = blockIdx.x * 256 + threadIdx.x;
  if (idx < N2) {
    int b = idx >> 15, rr = idx & 32767;
    int c = rr >> 10, oy = (rr >> 5) & 31, ox = rr & 31;
    float w = bilin64(SWb + ((b * 128 + 32 + c) << 12), oy, ox, 31);
    out[N1 + idx] = x2[idx] * (1.f + w);
  } else if (idx < N2 + N3) {
    int i3 = idx - N2;
    int b = i3 >> 13, rr = i3 & 8191;
    int c = rr >> 8, oy = (rr >> 4) & 15, ox = rr & 15;
    float w = bilin64(SWb + ((b * 128 + 64 + c) << 12), oy, ox, 15);
    out[N1 + idx] = x3[i3] * (1.f + w);
  } else if (idx < N2 + N3 + N4) {
    int i4 = idx - N2 - N3;
    int b = i4 >> 11, rr = i4 & 2047;
    int c = rr >> 6, oy = (rr >> 3) & 7, ox = rr & 7;
    float w = bilin64(SWb + ((b * 128 + 96 + c) << 12), oy, ox, 7);
    out[N1 + idx] = x4[i4] * (1.f + w);
  }
}

// ---------------------------------------------------------------------------
extern "C" void kernel_launch(void* const* d_in, const int* in_sizes, int n_in,
                              void* d_out, int out_size, void* d_ws, size_t ws_size,
                              hipStream_t stream) {
  const float* x1  = (const float*)d_in[0];
  const float* x2  = (const float*)d_in[1];
  const float* x3  = (const float*)d_in[2];
  const float* x4  = (const float*)d_in[3];
  const float* qw  = (const float*)d_in[4];
  const float* qb  = (const float*)d_in[5];
  const float* kw  = (const float*)d_in[6];
  const float* kb  = (const float*)d_in[7];
  const float* vw  = (const float*)d_in[8];
  const float* vb  = (const float*)d_in[9];
  const float* ow  = (const float*)d_in[10];
  const float* ob  = (const float*)d_in[11];
  const float* g1w = (const float*)d_in[12];
  const float* g1b = (const float*)d_in[13];
  const float* g2w = (const float*)d_in[14];
  const float* g2b = (const float*)d_in[15];
  float* out = (float*)d_out;

  char* ws = (char*)d_ws;
  unsigned short* Qg  = (unsigned short*)(ws + 0);
  unsigned short* Kg  = (unsigned short*)(ws + 4194304);
  unsigned short* Vg  = (unsigned short*)(ws + 8388608);
  unsigned short* SWb = (unsigned short*)(ws + 0);          // aliases Q/K (dead)
  unsigned short* Op  = (unsigned short*)(ws + 12582912);
  float* Lp   = (float*)(ws + 29360128);

  k_qkv<<<1024, 256, 0, stream>>>(x1, x2, x3, x4, qw, qb, kw, kb, vw, vb,
                                  Qg, Kg, Vg);
  k_attn<<<1024, 256, 0, stream>>>(Qg, Kg, Vg, Op, Lp);
  k_out<<<1024, 256, 0, stream>>>(Op, Lp, ow, ob, g1w, g1b, g2w, g2b,
                                  x1, out, SWb);
  k_final<<<1344, 256, 0, stream>>>(x2, x3, x4, SWb, out);
}